// Round 6
// baseline (16508.163 us; speedup 1.0000x reference)
//
#include <hip/hip_runtime.h>
#include <hip/hip_bf16.h>
#include <math.h>

#define S 256
#define H 1024
#define SH (S*H)
#define EPS 1e-5f

typedef float f32x4 __attribute__((ext_vector_type(4)));
typedef short bf16x8 __attribute__((ext_vector_type(8)));

__device__ __forceinline__ float sigm(float x){ return 1.0f/(1.0f+expf(-x)); }

__device__ __forceinline__ ushort f2bf(float a){
    union { __hip_bfloat16 b; ushort u; } cv;
    cv.b = __float2bfloat16(a);
    return cv.u;
}
__device__ __forceinline__ float bf2f(ushort u){
    union { __hip_bfloat16 b; ushort u; } cv; cv.u = u;
    return __bfloat162float(cv.b);
}

// bijective for 256 blocks: XCD x (blockIdx&7) gets g in [32x,32x+32)
// -> jb in [4x,4x+4): its 4 col-slabs of W stay XCD-local.
__device__ __forceinline__ int xcd_swizzle(unsigned gbx) {
    return (int)((gbx & 7u) * 32u + (gbx >> 3));
}

// ---------------------------------------------------------------------------
// Pack W[j][k] (fp32 HxH) into MFMA B-fragment layout, bf16 hi/lo split
// (identical to R3, verified): Wp[jt][ktg][lane][e] =
//   W[jt*16+(lane&15)][ktg*32+(lane>>4)*8+e]
// ---------------------------------------------------------------------------
__global__ __launch_bounds__(256) void k_pack(const float* __restrict__ W,
                                              ushort* __restrict__ ph,
                                              ushort* __restrict__ pl) {
    int p  = blockIdx.x * 256 + threadIdx.x;
    int l  = p & 63;
    int kt = (p >> 6) & 31;
    int jt = p >> 11;
    int j  = jt * 16 + (l & 15);
    int k0 = kt * 32 + ((l >> 4) << 3);
    const float* src = W + j * H + k0;
    float4 a0 = *(const float4*)src;
    float4 a1 = *(const float4*)(src + 4);
    float av[8] = {a0.x,a0.y,a0.z,a0.w,a1.x,a1.y,a1.z,a1.w};
    bf16x8 vh, vl;
#pragma unroll
    for (int e = 0; e < 8; ++e) {
        ushort h = f2bf(av[e]);
        vh[e] = (short)h;
        vl[e] = (short)f2bf(av[e] - bf2f(h));
    }
    *(bf16x8*)(ph + (size_t)p * 8) = vh;
    *(bf16x8*)(pl + (size_t)p * 8) = vl;
}

// ---------------------------------------------------------------------------
// Init: zero both stats parities + barrier counter/flag.
// ---------------------------------------------------------------------------
__global__ __launch_bounds__(256) void k_init(float* __restrict__ stats,
                                              unsigned* __restrict__ sync) {
    int t = blockIdx.x * 256 + threadIdx.x;
    if (t < 8 * H) stats[t] = 0.0f;
    if (t == 0) { sync[0] = 0u; sync[64] = 0u; }
}

// ---------------------------------------------------------------------------
// Grid barrier: monotonic arrive counter + release flag. All 256 blocks are
// guaranteed resident (1 block/CU). threadfence on both sides gives
// device-scope (cross-XCD) visibility of phase writes.
// ---------------------------------------------------------------------------
__device__ __forceinline__ void grid_barrier(unsigned* ctrp, unsigned* flagp,
                                             unsigned want) {
    __syncthreads();
    if (threadIdx.x == 0) {
        __threadfence();
        unsigned old = __hip_atomic_fetch_add(ctrp, 1u, __ATOMIC_RELAXED,
                                              __HIP_MEMORY_SCOPE_AGENT);
        if (old == want * 256u - 1u) {
            __hip_atomic_store(flagp, want, __ATOMIC_RELEASE,
                               __HIP_MEMORY_SCOPE_AGENT);
        } else {
            while (__hip_atomic_load(flagp, __ATOMIC_RELAXED,
                                     __HIP_MEMORY_SCOPE_AGENT) < want)
                __builtin_amdgcn_s_sleep(1);
        }
        __threadfence();
    }
    __syncthreads();
}

// ---------------------------------------------------------------------------
// Persistent kernel: 256 steps, 2 grid barriers each.
// Phase A: BN tables from prev stats; x1 = sig((X+hf)@W1^T+b1) via LDS-staged
//          bf16x3 MFMA; epilogue writes A2=hb+x1, A3=x1+hf as bf16 hi/lo
//          PLANES (split once here, consumed conversion-free in phase B).
// Phase B: hb2 = sig(A2@W2^T+b2), hf2 = sig(A3@W3^T+b3) as pure
//          global-load+MFMA loops; raw fp32 + stats atomics; out on last.
// ---------------------------------------------------------------------------
__global__ __launch_bounds__(256) void k_persist(
    const float* __restrict__ X,
    const ushort* __restrict__ wp1h, const ushort* __restrict__ wp1l,
    const ushort* __restrict__ wp2h, const ushort* __restrict__ wp2l,
    const ushort* __restrict__ wp3h, const ushort* __restrict__ wp3l,
    const float* __restrict__ b1v, const float* __restrict__ b2v,
    const float* __restrict__ b3v,
    const float* __restrict__ gFv, const float* __restrict__ bFv,
    const float* __restrict__ gBv, const float* __restrict__ bBv,
    ushort* __restrict__ A2h, ushort* __restrict__ A2l,
    ushort* __restrict__ A3h, ushort* __restrict__ A3l,
    float* __restrict__ rawf, float* __restrict__ rawb,
    float* __restrict__ stats, float* __restrict__ outp,
    unsigned* __restrict__ syncv)
{
    __shared__ __align__(16) ushort lhs_hi[8192];
    __shared__ __align__(16) ushort lhs_lo[8192];
    __shared__ float scF[H], ofF[H];
    __shared__ float red[4][64][2];

    const int t = threadIdx.x;
    const int g = xcd_swizzle(blockIdx.x);
    const int sb = g & 7, jb = g >> 3;
    const int lane = t & 63, w = t >> 6;
    const int wr = w >> 1, wc = w & 1;
    const int row0 = sb * 32;
    const int jt = jb * 2 + wc;
    const int j = jt * 16 + (lane & 15);
    const int arow = row0 + wr * 16 + (lane & 15);   // A-fragment row
    const int koff = (lane >> 4) << 3;               // A-fragment k offset
    const int srow = row0 + wr * 16 + ((lane >> 4) << 2);  // C row base
    const float inv = 1.0f / (float)S;

    unsigned* ctrp  = syncv;
    unsigned* flagp = syncv + 64;
    unsigned bgen = 0;

    for (int s = 0; s < S; ++s) {
        const int p = (s + 1) & 1, q = s & 1;
        const int first = (s == 0);
        const float* stP = stats + q * 4 * H;
        float* stA = stats + p * 4 * H;
        const float* rF = rawf + q * SH;
        const float* rB = rawb + q * SH;
        float* wF = rawf + p * SH;
        float* wB = rawb + p * SH;

        // ================= PHASE A =================
        if (!first) {
            for (int k = t; k < H; k += 256) {
                float m = stP[k] * inv;
                float v = stP[H + k] * inv - m * m;
                float sc = rsqrtf(v + EPS) * gFv[k];
                scF[k] = sc;
                ofF[k] = bFv[k] - m * sc;
            }
        }
        __syncthreads();

        {
            f32x4 acc0 = {0,0,0,0}, acc1 = {0,0,0,0}, acc2 = {0,0,0,0};
            for (int phase = 0; phase < 4; ++phase) {
                int kbase = phase << 8;
#pragma unroll
                for (int it = 0; it < 4; ++it) {
                    int gg = t + (it << 8);
                    int si = gg & 31, kg = gg >> 5;
                    int k = kbase + (kg << 3);
                    const float* xp = X + (row0 + si) * H + k;
                    float4 x0 = *(const float4*)xp;
                    float4 x1 = *(const float4*)(xp + 4);
                    float a[8] = {x0.x,x0.y,x0.z,x0.w,x1.x,x1.y,x1.z,x1.w};
                    if (!first) {
                        const float* rp = rF + (row0 + si) * H + k;
                        float4 r0 = *(const float4*)rp;
                        float4 r1 = *(const float4*)(rp + 4);
                        float rr[8] = {r0.x,r0.y,r0.z,r0.w,r1.x,r1.y,r1.z,r1.w};
#pragma unroll
                        for (int e = 0; e < 8; ++e)
                            a[e] += rr[e] * scF[k + e] + ofF[k + e];
                    }
                    bf16x8 vh, vl;
#pragma unroll
                    for (int e = 0; e < 8; ++e) {
                        ushort h = f2bf(a[e]);
                        vh[e] = (short)h;
                        vl[e] = (short)f2bf(a[e] - bf2f(h));
                    }
                    int idx = ((((si >> 4) * 8 + (kg >> 2)) * 64) +
                               (((kg & 3) << 4) | (si & 15))) * 8;
                    *(bf16x8*)(lhs_hi + idx) = vh;
                    *(bf16x8*)(lhs_lo + idx) = vl;
                }
                __syncthreads();
                const ushort* bph = wp1h + ((size_t)(jt * 32 + (phase << 3)) * 64 + lane) * 8;
                const ushort* bpl = wp1l + ((size_t)(jt * 32 + (phase << 3)) * 64 + lane) * 8;
                const ushort* ah  = lhs_hi + ((wr * 8) * 64 + lane) * 8;
                const ushort* al  = lhs_lo + ((wr * 8) * 64 + lane) * 8;
#pragma unroll
                for (int kc = 0; kc < 8; ++kc) {
                    bf16x8 a_h = *(const bf16x8*)(ah + kc * 512);
                    bf16x8 a_l = *(const bf16x8*)(al + kc * 512);
                    bf16x8 b_h = *(const bf16x8*)(bph + kc * 512);
                    bf16x8 b_l = *(const bf16x8*)(bpl + kc * 512);
                    acc0 = __builtin_amdgcn_mfma_f32_16x16x32_bf16(a_h, b_h, acc0, 0, 0, 0);
                    acc1 = __builtin_amdgcn_mfma_f32_16x16x32_bf16(a_h, b_l, acc1, 0, 0, 0);
                    acc2 = __builtin_amdgcn_mfma_f32_16x16x32_bf16(a_l, b_h, acc2, 0, 0, 0);
                }
                __syncthreads();
            }

            float bias = b1v[j];
            float scFj = 0.f, ofFj = 0.f, scBj = 0.f, ofBj = 0.f;
            if (!first) {
                scFj = scF[j]; ofFj = ofF[j];
                float m = stP[2 * H + j] * inv;
                float v = stP[3 * H + j] * inv - m * m;
                scBj = rsqrtf(v + EPS) * gBv[j];
                ofBj = bBv[j] - m * scBj;
            }
            f32x4 sum = acc0 + acc1 + acc2;
#pragma unroll
            for (int r = 0; r < 4; ++r) {
                int o = (srow + r) * H + j;
                float x1v = sigm(sum[r] + bias);
                float hb_ = first ? 0.f : rB[o] * scBj + ofBj;
                float hf_ = first ? 0.f : rF[o] * scFj + ofFj;
                float a2 = hb_ + x1v;
                float a3 = x1v + hf_;
                ushort h2 = f2bf(a2);
                A2h[o] = h2;
                A2l[o] = f2bf(a2 - bf2f(h2));
                ushort h3 = f2bf(a3);
                A3h[o] = h3;
                A3l[o] = f2bf(a3 - bf2f(h3));
            }
        }

        grid_barrier(ctrp, flagp, ++bgen);

        // ================= PHASE B =================
        // retire consumed stats buffer (reused for accumulation at step s+1)
        if (blockIdx.x == 0) {
            float* z = stats + q * 4 * H;
            for (int k = t; k < 4 * H; k += 256) z[k] = 0.0f;
        }

        float vb[4];
        // ---- GEMM2: hb2 = sig(A2 @ W2^T + b2) ----
        {
            f32x4 acc0 = {0,0,0,0}, acc1 = {0,0,0,0}, acc2 = {0,0,0,0};
            const ushort* ah = A2h + arow * H + koff;
            const ushort* al = A2l + arow * H + koff;
            const ushort* bh = wp2h + ((size_t)(jt * 32) * 64 + lane) * 8;
            const ushort* bl = wp2l + ((size_t)(jt * 32) * 64 + lane) * 8;
#pragma unroll 8
            for (int kc = 0; kc < 32; ++kc) {
                bf16x8 vah = *(const bf16x8*)(ah + kc * 32);
                bf16x8 val = *(const bf16x8*)(al + kc * 32);
                bf16x8 vbh = *(const bf16x8*)(bh + kc * 512);
                bf16x8 vbl = *(const bf16x8*)(bl + kc * 512);
                acc0 = __builtin_amdgcn_mfma_f32_16x16x32_bf16(vah, vbh, acc0, 0, 0, 0);
                acc1 = __builtin_amdgcn_mfma_f32_16x16x32_bf16(vah, vbl, acc1, 0, 0, 0);
                acc2 = __builtin_amdgcn_mfma_f32_16x16x32_bf16(val, vbh, acc2, 0, 0, 0);
            }
            f32x4 sum = acc0 + acc1 + acc2;
            float bias = b2v[j];
            float ts = 0.f, tq = 0.f;
#pragma unroll
            for (int r = 0; r < 4; ++r) {
                float v = sigm(sum[r] + bias);
                vb[r] = v;
                wB[(srow + r) * H + j] = v;
                ts += v; tq += v * v;
            }
            red[w][lane][0] = ts;
            red[w][lane][1] = tq;
        }
        __syncthreads();
        if (t < 32) {
            int wc2 = t >> 4, jl = t & 15;
            int jj = jb * 32 + wc2 * 16 + jl;
            float ts = 0.f, tq = 0.f;
#pragma unroll
            for (int wr2 = 0; wr2 < 2; ++wr2)
#pragma unroll
                for (int lg = 0; lg < 4; ++lg) {
                    ts += red[wr2 * 2 + wc2][lg * 16 + jl][0];
                    tq += red[wr2 * 2 + wc2][lg * 16 + jl][1];
                }
            atomicAdd(&stA[2 * H + jj], ts);
            atomicAdd(&stA[3 * H + jj], tq);
        }
        __syncthreads();

        // ---- GEMM3: hf2 = sig(A3 @ W3^T + b3) ----
        {
            f32x4 acc0 = {0,0,0,0}, acc1 = {0,0,0,0}, acc2 = {0,0,0,0};
            const ushort* ah = A3h + arow * H + koff;
            const ushort* al = A3l + arow * H + koff;
            const ushort* bh = wp3h + ((size_t)(jt * 32) * 64 + lane) * 8;
            const ushort* bl = wp3l + ((size_t)(jt * 32) * 64 + lane) * 8;
#pragma unroll 8
            for (int kc = 0; kc < 32; ++kc) {
                bf16x8 vah = *(const bf16x8*)(ah + kc * 32);
                bf16x8 val = *(const bf16x8*)(al + kc * 32);
                bf16x8 vbh = *(const bf16x8*)(bh + kc * 512);
                bf16x8 vbl = *(const bf16x8*)(bl + kc * 512);
                acc0 = __builtin_amdgcn_mfma_f32_16x16x32_bf16(vah, vbh, acc0, 0, 0, 0);
                acc1 = __builtin_amdgcn_mfma_f32_16x16x32_bf16(vah, vbl, acc1, 0, 0, 0);
                acc2 = __builtin_amdgcn_mfma_f32_16x16x32_bf16(val, vbh, acc2, 0, 0, 0);
            }
            f32x4 sum = acc0 + acc1 + acc2;
            float bias = b3v[j];
            float ts = 0.f, tq = 0.f;
#pragma unroll
            for (int r = 0; r < 4; ++r) {
                float v = sigm(sum[r] + bias);
                wF[(srow + r) * H + j] = v;
                if (s == S - 1)
                    outp[(srow + r) * H + j] = 0.5f * (v + vb[r]);
                ts += v; tq += v * v;
            }
            red[w][lane][0] = ts;
            red[w][lane][1] = tq;
        }
        __syncthreads();
        if (t < 32) {
            int wc2 = t >> 4, jl = t & 15;
            int jj = jb * 32 + wc2 * 16 + jl;
            float ts = 0.f, tq = 0.f;
#pragma unroll
            for (int wr2 = 0; wr2 < 2; ++wr2)
#pragma unroll
                for (int lg = 0; lg < 4; ++lg) {
                    ts += red[wr2 * 2 + wc2][lg * 16 + jl][0];
                    tq += red[wr2 * 2 + wc2][lg * 16 + jl][1];
                }
            atomicAdd(&stA[0 * H + jj], ts);
            atomicAdd(&stA[1 * H + jj], tq);
        }

        if (s != S - 1)
            grid_barrier(ctrp, flagp, ++bgen);
    }
}

// ---------------------------------------------------------------------------
// Host: 5 graph nodes total (3 pack + init + persistent).
// Dead in reference: LSTM cells (discarded carry), W4/b4, all outs but last.
// ---------------------------------------------------------------------------
extern "C" void kernel_launch(void* const* d_in, const int* in_sizes, int n_in,
                              void* d_out, int out_size, void* d_ws, size_t ws_size,
                              hipStream_t stream) {
    (void)in_sizes; (void)n_in; (void)out_size; (void)ws_size;

    const float* X  = (const float*)d_in[0];
    const float* W1 = (const float*)d_in[1];
    const float* b1 = (const float*)d_in[2];
    const float* W2 = (const float*)d_in[3];
    const float* b2 = (const float*)d_in[4];
    const float* W3 = (const float*)d_in[5];
    const float* b3 = (const float*)d_in[6];
    const float* gf = (const float*)d_in[17];
    const float* bf = (const float*)d_in[18];
    const float* gb = (const float*)d_in[19];
    const float* bb = (const float*)d_in[20];

    char* base = (char*)d_ws;
    const size_t MB = 1024 * 1024;
    ushort* wp1h = (ushort*)(base + 0 * MB);
    ushort* wp1l = (ushort*)(base + 2 * MB);
    ushort* wp2h = (ushort*)(base + 4 * MB);
    ushort* wp2l = (ushort*)(base + 6 * MB);
    ushort* wp3h = (ushort*)(base + 8 * MB);
    ushort* wp3l = (ushort*)(base + 10 * MB);
    ushort* A2h  = (ushort*)(base + 12 * MB);            // 512KB each
    ushort* A2l  = (ushort*)(base + 12 * MB + 512 * 1024);
    ushort* A3h  = (ushort*)(base + 13 * MB);
    ushort* A3l  = (ushort*)(base + 13 * MB + 512 * 1024);
    float*  rawf = (float*)(base + 14 * MB);             // 2 parities x 1MB
    float*  rawb = (float*)(base + 16 * MB);             // 2 parities x 1MB
    float*  stats= (float*)(base + 18 * MB);             // 2 parities x 16KB
    unsigned* syncv = (unsigned*)(base + 18 * MB + 64 * 1024);

    k_pack<<<512, 256, 0, stream>>>(W1, wp1h, wp1l);
    k_pack<<<512, 256, 0, stream>>>(W2, wp2h, wp2l);
    k_pack<<<512, 256, 0, stream>>>(W3, wp3h, wp3l);
    k_init<<<33, 256, 0, stream>>>(stats, syncv);

    k_persist<<<256, 256, 0, stream>>>(
        X, wp1h, wp1l, wp2h, wp2l, wp3h, wp3l,
        b1, b2, b3, gf, bf, gb, bb,
        A2h, A2l, A3h, A3l,
        rawf, rawb, stats, (float*)d_out, syncv);
}

// Round 7
// 15223.022 us; speedup vs baseline: 1.0844x; 1.0844x over previous
//
#include <hip/hip_runtime.h>
#include <hip/hip_bf16.h>
#include <math.h>

#define S 256
#define H 1024
#define SH (S*H)
#define EPS 1e-5f

typedef float f32x4 __attribute__((ext_vector_type(4)));
typedef short bf16x8 __attribute__((ext_vector_type(8)));

__device__ __forceinline__ float sigm(float x){ return 1.0f/(1.0f+expf(-x)); }

__device__ __forceinline__ ushort f2bf(float a){
    union { __hip_bfloat16 b; ushort u; } cv;
    cv.b = __float2bfloat16(a);
    return cv.u;
}
__device__ __forceinline__ float bf2f(ushort u){
    union { __hip_bfloat16 b; ushort u; } cv; cv.u = u;
    return __bfloat162float(cv.b);
}

// bijective for 256 blocks: XCD x (blockIdx&7) gets g in [32x,32x+32)
// -> jb in [4x,4x+4): its 4 col-slabs of W stay XCD-local.
__device__ __forceinline__ int xcd_swizzle(unsigned gbx) {
    return (int)((gbx & 7u) * 32u + (gbx >> 3));
}

// ---------------------------------------------------------------------------
// Pack W[j][k] (fp32 HxH) into MFMA B-fragment layout, bf16 hi/lo split
// (identical to R3, verified): Wp[jt][kt][lane][e] =
//   W[jt*16+(lane&15)][kt*32+(lane>>4)*8+e]
// ---------------------------------------------------------------------------
__global__ __launch_bounds__(256) void k_pack(const float* __restrict__ W,
                                              ushort* __restrict__ ph,
                                              ushort* __restrict__ pl) {
    int p  = blockIdx.x * 256 + threadIdx.x;
    int l  = p & 63;
    int kt = (p >> 6) & 31;
    int jt = p >> 11;
    int j  = jt * 16 + (l & 15);
    int k0 = kt * 32 + ((l >> 4) << 3);
    const float* src = W + j * H + k0;
    float4 a0 = *(const float4*)src;
    float4 a1 = *(const float4*)(src + 4);
    float av[8] = {a0.x,a0.y,a0.z,a0.w,a1.x,a1.y,a1.z,a1.w};
    bf16x8 vh, vl;
#pragma unroll
    for (int e = 0; e < 8; ++e) {
        ushort h = f2bf(av[e]);
        vh[e] = (short)h;
        vl[e] = (short)f2bf(av[e] - bf2f(h));
    }
    *(bf16x8*)(ph + (size_t)p * 8) = vh;
    *(bf16x8*)(pl + (size_t)p * 8) = vl;
}

// ---------------------------------------------------------------------------
// Init: zero both stats parities + all barrier state.
// ---------------------------------------------------------------------------
__global__ __launch_bounds__(256) void k_init(float* __restrict__ stats,
                                              unsigned* __restrict__ sync) {
    int t = blockIdx.x * 256 + threadIdx.x;
    if (t < 8 * H) stats[t] = 0.0f;
    if (t < 64) sync[t] = 0u;
}

// ---------------------------------------------------------------------------
// Two-level grid barrier: 8 per-XCD arrive counters (32 blocks each) ->
// master counter (8 arrivals) -> release flag. Monotonic generations, no
// reset. threadfence both sides for cross-XCD visibility (L2 flush/inv).
// syncv layout: [0..7] xcd counters, [16] master, [32] flag.
// ---------------------------------------------------------------------------
__device__ __forceinline__ void grid_barrier(unsigned* __restrict__ syncv,
                                             unsigned want, int xid) {
    __syncthreads();
    if (threadIdx.x == 0) {
        __threadfence();
        unsigned old = __hip_atomic_fetch_add(&syncv[xid], 1u, __ATOMIC_RELAXED,
                                              __HIP_MEMORY_SCOPE_AGENT);
        if (old == want * 32u - 1u) {
            unsigned m = __hip_atomic_fetch_add(&syncv[16], 1u, __ATOMIC_RELAXED,
                                                __HIP_MEMORY_SCOPE_AGENT);
            if (m == want * 8u - 1u)
                __hip_atomic_store(&syncv[32], want, __ATOMIC_RELEASE,
                                   __HIP_MEMORY_SCOPE_AGENT);
        }
        while (__hip_atomic_load(&syncv[32], __ATOMIC_RELAXED,
                                 __HIP_MEMORY_SCOPE_AGENT) < want)
            __builtin_amdgcn_s_sleep(1);
        __threadfence();
    }
    __syncthreads();
}

// ---------------------------------------------------------------------------
// Persistent kernel, 512 threads (8 waves), split-K x2:
//  waves 0-3 (kh=0) own K [0,512), waves 4-7 (kh=1) own K [512,1024);
//  per K-half a wave computes one 16x16 tile of the block's 32x32 output.
//  Partial accumulators summed via LDS (redK). Doubles waves/SIMD (1->2)
//  to double outstanding memory requests (R6 profile: 92% latency-stalled).
// Phase A: full-K LDS stage of BN-fused A1 (bf16 hi/lo), GEMM1, epilogue
//          writes A2/A3 bf16 hi/lo planes.
// Phase B: GEMM2 (hb2->rawB+stats), GEMM3 (hf2->rawF+stats), pure
//          global-load+MFMA; final step writes out = 0.5*(hf2+hb2).
// ---------------------------------------------------------------------------
__global__ __launch_bounds__(512, 2) void k_persist(
    const float* __restrict__ X,
    const ushort* __restrict__ wp1h, const ushort* __restrict__ wp1l,
    const ushort* __restrict__ wp2h, const ushort* __restrict__ wp2l,
    const ushort* __restrict__ wp3h, const ushort* __restrict__ wp3l,
    const float* __restrict__ b1v, const float* __restrict__ b2v,
    const float* __restrict__ b3v,
    const float* __restrict__ gFv, const float* __restrict__ bFv,
    const float* __restrict__ gBv, const float* __restrict__ bBv,
    ushort* __restrict__ A2h, ushort* __restrict__ A2l,
    ushort* __restrict__ A3h, ushort* __restrict__ A3l,
    float* __restrict__ rawf, float* __restrict__ rawb,
    float* __restrict__ stats, float* __restrict__ outp,
    unsigned* __restrict__ syncv)
{
    // 82 KB static LDS (1 block/CU by design; 8 waves = 2/SIMD)
    __shared__ __align__(16) ushort lhs_hi[32768];   // [64 chunks][64 lane][8]
    __shared__ __align__(16) ushort lhs_lo[32768];
    __shared__ float scF[H], ofF[H];                 // 8 KB BN-F tables
    __shared__ __align__(16) float redK[8][64][4];   // split-K partial sums
    __shared__ float redS[4][64][2];                 // stats reduction

    const int t = threadIdx.x;
    const int bx = blockIdx.x;
    const int xid = bx & 7;
    const int g = xcd_swizzle(bx);
    const int sb = g & 7, jb = g >> 3;
    const int lane = t & 63, w = t >> 6;       // 8 waves
    const int kh = w >> 2;                     // K-half
    const int ws = w & 3;                      // tile wave
    const int wr = ws >> 1, wc = ws & 1;
    const int row0 = sb * 32;
    const int jt = jb * 2 + wc;
    const int j = jt * 16 + (lane & 15);
    const int arow = row0 + wr * 16 + (lane & 15);        // A-frag row
    const int koff = (lane >> 4) << 3;                    // A-frag k sub
    const int srow = row0 + wr * 16 + ((lane >> 4) << 2); // C row base
    const float inv = 1.0f / (float)S;

    unsigned bgen = 0;

    for (int s = 0; s < S; ++s) {
        const int p = (s + 1) & 1, q = s & 1;
        const int first = (s == 0);
        const float* stP = stats + q * 4 * H;
        float* stA = stats + p * 4 * H;
        const float* rF = rawf + q * SH;
        const float* rB = rawb + q * SH;
        float* wF = rawf + p * SH;
        float* wB = rawb + p * SH;

        // ================= PHASE A =================
        if (!first) {
            for (int k = t; k < H; k += 512) {
                float m = stP[k] * inv;
                float v = stP[H + k] * inv - m * m;
                float sc = rsqrtf(v + EPS) * gFv[k];
                scF[k] = sc;
                ofF[k] = bFv[k] - m * sc;
            }
        }
        __syncthreads();

        // stage full-K A1 = X + BN_F(rawF) as bf16 hi/lo into LDS
#pragma unroll
        for (int it = 0; it < 8; ++it) {
            int gi = t + (it << 9);            // 0..4095
            int si = gi & 31;
            int kg = gi >> 5;                  // 0..127
            int k = kg << 3;
            const float* xp = X + (row0 + si) * H + k;
            float4 x0 = *(const float4*)xp;
            float4 x1 = *(const float4*)(xp + 4);
            float a[8] = {x0.x,x0.y,x0.z,x0.w,x1.x,x1.y,x1.z,x1.w};
            if (!first) {
                const float* rp = rF + (row0 + si) * H + k;
                float4 r0 = *(const float4*)rp;
                float4 r1 = *(const float4*)(rp + 4);
                float rr[8] = {r0.x,r0.y,r0.z,r0.w,r1.x,r1.y,r1.z,r1.w};
#pragma unroll
                for (int e = 0; e < 8; ++e)
                    a[e] += rr[e] * scF[k + e] + ofF[k + e];
            }
            bf16x8 vh, vl;
#pragma unroll
            for (int e = 0; e < 8; ++e) {
                ushort h = f2bf(a[e]);
                vh[e] = (short)h;
                vl[e] = (short)f2bf(a[e] - bf2f(h));
            }
            // chunk = (rowhalf)*32 + kc32 ; laneslot = (ksub<<4)|(row&15)
            int idx = ((((si >> 4) * 32 + (kg >> 2)) * 64) +
                       (((kg & 3) << 4) | (si & 15))) * 8;
            *(bf16x8*)(lhs_hi + idx) = vh;
            *(bf16x8*)(lhs_lo + idx) = vl;
        }
        __syncthreads();

        {
            f32x4 acc0 = {0,0,0,0}, acc1 = {0,0,0,0}, acc2 = {0,0,0,0};
            const int cbase = wr * 32 + kh * 16;
            const ushort* ah  = lhs_hi + (cbase * 64 + lane) * 8;
            const ushort* al  = lhs_lo + (cbase * 64 + lane) * 8;
            const ushort* bph = wp1h + ((size_t)(jt * 32 + kh * 16) * 64 + lane) * 8;
            const ushort* bpl = wp1l + ((size_t)(jt * 32 + kh * 16) * 64 + lane) * 8;
#pragma unroll 8
            for (int kc = 0; kc < 16; ++kc) {
                bf16x8 a_h = *(const bf16x8*)(ah + kc * 512);
                bf16x8 a_l = *(const bf16x8*)(al + kc * 512);
                bf16x8 b_h = *(const bf16x8*)(bph + kc * 512);
                bf16x8 b_l = *(const bf16x8*)(bpl + kc * 512);
                acc0 = __builtin_amdgcn_mfma_f32_16x16x32_bf16(a_h, b_h, acc0, 0, 0, 0);
                acc1 = __builtin_amdgcn_mfma_f32_16x16x32_bf16(a_h, b_l, acc1, 0, 0, 0);
                acc2 = __builtin_amdgcn_mfma_f32_16x16x32_bf16(a_l, b_h, acc2, 0, 0, 0);
            }
            f32x4 part = acc0 + acc1 + acc2;
            *(f32x4*)&redK[w][lane][0] = part;
        }
        __syncthreads();

        if (kh == 0) {
            f32x4 sum = *(f32x4*)&redK[w][lane][0] + *(f32x4*)&redK[w + 4][lane][0];
            float bias = b1v[j];
            float scFj = 0.f, ofFj = 0.f, scBj = 0.f, ofBj = 0.f;
            if (!first) {
                scFj = scF[j]; ofFj = ofF[j];
                float m = stP[2 * H + j] * inv;
                float v = stP[3 * H + j] * inv - m * m;
                scBj = rsqrtf(v + EPS) * gBv[j];
                ofBj = bBv[j] - m * scBj;
            }
#pragma unroll
            for (int r = 0; r < 4; ++r) {
                int o = (srow + r) * H + j;
                float x1v = sigm(sum[r] + bias);
                float hb_ = first ? 0.f : rB[o] * scBj + ofBj;
                float hf_ = first ? 0.f : rF[o] * scFj + ofFj;
                float a2 = hb_ + x1v;
                float a3 = x1v + hf_;
                ushort h2 = f2bf(a2);
                A2h[o] = h2;
                A2l[o] = f2bf(a2 - bf2f(h2));
                ushort h3 = f2bf(a3);
                A3h[o] = h3;
                A3l[o] = f2bf(a3 - bf2f(h3));
            }
        }

        grid_barrier(syncv, ++bgen, xid);

        // ================= PHASE B =================
        // retire consumed stats parity (8 blocks x 512 threads = 4H floats)
        if (bx < 8) {
            float* z = stats + q * 4 * H;
            z[bx * 512 + t] = 0.0f;
        }

        float vb[4] = {0,0,0,0};

        // ---- GEMM2: hb2 = sig(A2 @ W2^T + b2) ----
        {
            f32x4 acc0 = {0,0,0,0}, acc1 = {0,0,0,0}, acc2 = {0,0,0,0};
            const ushort* ah = A2h + (size_t)arow * H + kh * 512 + koff;
            const ushort* al = A2l + (size_t)arow * H + kh * 512 + koff;
            const ushort* bh = wp2h + ((size_t)(jt * 32 + kh * 16) * 64 + lane) * 8;
            const ushort* bl = wp2l + ((size_t)(jt * 32 + kh * 16) * 64 + lane) * 8;
#pragma unroll 8
            for (int kc = 0; kc < 16; ++kc) {
                bf16x8 vah = *(const bf16x8*)(ah + kc * 32);
                bf16x8 val = *(const bf16x8*)(al + kc * 32);
                bf16x8 vbh = *(const bf16x8*)(bh + kc * 512);
                bf16x8 vbl = *(const bf16x8*)(bl + kc * 512);
                acc0 = __builtin_amdgcn_mfma_f32_16x16x32_bf16(vah, vbh, acc0, 0, 0, 0);
                acc1 = __builtin_amdgcn_mfma_f32_16x16x32_bf16(vah, vbl, acc1, 0, 0, 0);
                acc2 = __builtin_amdgcn_mfma_f32_16x16x32_bf16(val, vbh, acc2, 0, 0, 0);
            }
            f32x4 part = acc0 + acc1 + acc2;
            *(f32x4*)&redK[w][lane][0] = part;
        }
        __syncthreads();
        if (kh == 0) {
            f32x4 sum = *(f32x4*)&redK[w][lane][0] + *(f32x4*)&redK[w + 4][lane][0];
            float bias = b2v[j];
            float ts = 0.f, tq = 0.f;
#pragma unroll
            for (int r = 0; r < 4; ++r) {
                float v = sigm(sum[r] + bias);
                vb[r] = v;
                wB[(srow + r) * H + j] = v;
                ts += v; tq += v * v;
            }
            redS[ws][lane][0] = ts;
            redS[ws][lane][1] = tq;
        }
        __syncthreads();
        if (t < 32) {
            int wc2 = t >> 4, jl = t & 15;
            int jj = jb * 32 + wc2 * 16 + jl;
            float ts = 0.f, tq = 0.f;
#pragma unroll
            for (int wr2 = 0; wr2 < 2; ++wr2)
#pragma unroll
                for (int lg = 0; lg < 4; ++lg) {
                    ts += redS[wr2 * 2 + wc2][lg * 16 + jl][0];
                    tq += redS[wr2 * 2 + wc2][lg * 16 + jl][1];
                }
            atomicAdd(&stA[2 * H + jj], ts);
            atomicAdd(&stA[3 * H + jj], tq);
        }

        // ---- GEMM3: hf2 = sig(A3 @ W3^T + b3) ----
        {
            f32x4 acc0 = {0,0,0,0}, acc1 = {0,0,0,0}, acc2 = {0,0,0,0};
            const ushort* ah = A3h + (size_t)arow * H + kh * 512 + koff;
            const ushort* al = A3l + (size_t)arow * H + kh * 512 + koff;
            const ushort* bh = wp3h + ((size_t)(jt * 32 + kh * 16) * 64 + lane) * 8;
            const ushort* bl = wp3l + ((size_t)(jt * 32 + kh * 16) * 64 + lane) * 8;
#pragma unroll 8
            for (int kc = 0; kc < 16; ++kc) {
                bf16x8 vah = *(const bf16x8*)(ah + kc * 32);
                bf16x8 val = *(const bf16x8*)(al + kc * 32);
                bf16x8 vbh = *(const bf16x8*)(bh + kc * 512);
                bf16x8 vbl = *(const bf16x8*)(bl + kc * 512);
                acc0 = __builtin_amdgcn_mfma_f32_16x16x32_bf16(vah, vbh, acc0, 0, 0, 0);
                acc1 = __builtin_amdgcn_mfma_f32_16x16x32_bf16(vah, vbl, acc1, 0, 0, 0);
                acc2 = __builtin_amdgcn_mfma_f32_16x16x32_bf16(val, vbh, acc2, 0, 0, 0);
            }
            f32x4 part = acc0 + acc1 + acc2;
            *(f32x4*)&redK[w][lane][0] = part;
        }
        __syncthreads();
        if (kh == 0) {
            f32x4 sum = *(f32x4*)&redK[w][lane][0] + *(f32x4*)&redK[w + 4][lane][0];
            float bias = b3v[j];
            float ts = 0.f, tq = 0.f;
#pragma unroll
            for (int r = 0; r < 4; ++r) {
                float v = sigm(sum[r] + bias);
                wF[(srow + r) * H + j] = v;
                if (s == S - 1)
                    outp[(srow + r) * H + j] = 0.5f * (v + vb[r]);
                ts += v; tq += v * v;
            }
            redS[ws][lane][0] = ts;
            redS[ws][lane][1] = tq;
        }
        __syncthreads();
        if (t < 32) {
            int wc2 = t >> 4, jl = t & 15;
            int jj = jb * 32 + wc2 * 16 + jl;
            float ts = 0.f, tq = 0.f;
#pragma unroll
            for (int wr2 = 0; wr2 < 2; ++wr2)
#pragma unroll
                for (int lg = 0; lg < 4; ++lg) {
                    ts += redS[wr2 * 2 + wc2][lg * 16 + jl][0];
                    tq += redS[wr2 * 2 + wc2][lg * 16 + jl][1];
                }
            atomicAdd(&stA[0 * H + jj], ts);
            atomicAdd(&stA[1 * H + jj], tq);
        }

        if (s != S - 1)
            grid_barrier(syncv, ++bgen, xid);
    }
}

// ---------------------------------------------------------------------------
// Host: 5 graph nodes (3 pack + init + persistent).
// Dead in reference: LSTM cells (discarded carry), W4/b4, all outs but last.
// ---------------------------------------------------------------------------
extern "C" void kernel_launch(void* const* d_in, const int* in_sizes, int n_in,
                              void* d_out, int out_size, void* d_ws, size_t ws_size,
                              hipStream_t stream) {
    (void)in_sizes; (void)n_in; (void)out_size; (void)ws_size;

    const float* X  = (const float*)d_in[0];
    const float* W1 = (const float*)d_in[1];
    const float* b1 = (const float*)d_in[2];
    const float* W2 = (const float*)d_in[3];
    const float* b2 = (const float*)d_in[4];
    const float* W3 = (const float*)d_in[5];
    const float* b3 = (const float*)d_in[6];
    const float* gf = (const float*)d_in[17];
    const float* bf = (const float*)d_in[18];
    const float* gb = (const float*)d_in[19];
    const float* bb = (const float*)d_in[20];

    char* base = (char*)d_ws;
    const size_t MB = 1024 * 1024;
    ushort* wp1h = (ushort*)(base + 0 * MB);
    ushort* wp1l = (ushort*)(base + 2 * MB);
    ushort* wp2h = (ushort*)(base + 4 * MB);
    ushort* wp2l = (ushort*)(base + 6 * MB);
    ushort* wp3h = (ushort*)(base + 8 * MB);
    ushort* wp3l = (ushort*)(base + 10 * MB);
    ushort* A2h  = (ushort*)(base + 12 * MB);            // 512KB each
    ushort* A2l  = (ushort*)(base + 12 * MB + 512 * 1024);
    ushort* A3h  = (ushort*)(base + 13 * MB);
    ushort* A3l  = (ushort*)(base + 13 * MB + 512 * 1024);
    float*  rawf = (float*)(base + 14 * MB);             // 2 parities x 1MB
    float*  rawb = (float*)(base + 16 * MB);             // 2 parities x 1MB
    float*  stats= (float*)(base + 18 * MB);             // 2 parities x 16KB
    unsigned* syncv = (unsigned*)(base + 18 * MB + 64 * 1024);

    k_pack<<<512, 256, 0, stream>>>(W1, wp1h, wp1l);
    k_pack<<<512, 256, 0, stream>>>(W2, wp2h, wp2l);
    k_pack<<<512, 256, 0, stream>>>(W3, wp3h, wp3l);
    k_init<<<33, 256, 0, stream>>>(stats, syncv);

    k_persist<<<256, 512, 0, stream>>>(
        X, wp1h, wp1l, wp2h, wp2l, wp3h, wp3l,
        b1, b2, b3, gf, bf, gb, bb,
        A2h, A2l, A3h, A3l,
        rawf, rawb, stats, (float*)d_out, syncv);
}